// Round 1
// baseline (10378.668 us; speedup 1.0000x reference)
//
#include <hip/hip_runtime.h>
#include <hip/hip_bf16.h>
#include <math.h>
#include <stdint.h>

#define NN 8192
#define EE 131072

#define PI_F     3.14159265358979323846f
#define SQRT3_F  1.7320508075688772f
#define INV_SQ2  0.7071067811865476f
#define INV_SQ3  0.5773502691896258f
#define INV_S32  0.17677669529663687f
#define INV_S96  0.10206207261596575f
#define INV_S10  0.31622776601683794f
#define C_S_F    0.3826834323650898f
#define C_X_F    0.9238795325112867f
#define EMB_S    2.8234621965789795f   /* sqrt(10)/1.12 */
#define OUT_S    0.044194173824159216f /* 1/sqrt(512)   */

__device__ __forceinline__ float sigmoid_f(float x){ return 1.0f/(1.0f+__expf(-x)); }

// ---------------- edge geometry: r, cutoff, y1, radial basis ----------------
__global__ __launch_bounds__(256) void k_geom(const float* __restrict__ ev,
    float* __restrict__ y0, float* __restrict__ y1, float* __restrict__ emb)
{
    int e = blockIdx.x*256 + threadIdx.x;
    float vx=ev[e*3+0], vy=ev[e*3+1], vz=ev[e*3+2];
    float r = sqrtf(vx*vx+vy*vy+vz*vz);
    float uu = 0.5f*r - 2.0f;                 // u = 2*(r/4 - 1)
    float cut;
    if (uu > 0.0f)       cut = 0.0f;
    else if (uu < -1.0f) cut = 1.0f;
    else                 cut = 0.5f*(1.0f - cosf(PI_F*uu));
    y0[e] = cut;
    float s = SQRT3_F*cut/(r + 1e-12f);
    y1[e*3+0]=vx*s; y1[e*3+1]=vy*s; y1[e*3+2]=vz*s;
    #pragma unroll
    for(int b=0;b<10;b++){
        float d = r*2.25f - (float)b;         // (r - b*4/9)/(4/9)
        emb[e*10+b] = __expf(-d*d)*EMB_S;
    }
}

// ---------------- CSR build (sort edges by dst) ----------------
__global__ __launch_bounds__(256) void k_count(const int* __restrict__ dst, int* __restrict__ cnt)
{
    int e = blockIdx.x*256 + threadIdx.x;
    atomicAdd(&cnt[dst[e]], 1);
}

__global__ __launch_bounds__(1024) void k_scan(const int* __restrict__ cnt,
    int* __restrict__ off, int* __restrict__ cur)
{
    __shared__ int partial[1024];
    int t = threadIdx.x;
    int base = t*8;
    int local[8];
    int s = 0;
    #pragma unroll
    for(int i=0;i<8;i++){ local[i]=s; s += cnt[base+i]; }
    partial[t] = s;
    __syncthreads();
    for(int d=1; d<1024; d<<=1){
        int v = (t>=d) ? partial[t-d] : 0;
        __syncthreads();
        partial[t] += v;
        __syncthreads();
    }
    int pref = (t>0) ? partial[t-1] : 0;
    #pragma unroll
    for(int i=0;i<8;i++){
        int o = pref + local[i];
        off[base+i] = o; cur[base+i] = o;
    }
    if (t==1023) off[NN] = partial[1023];
}

__global__ __launch_bounds__(256) void k_scatter(const int* __restrict__ dst,
    int* __restrict__ cur, int* __restrict__ eids)
{
    int e = blockIdx.x*256 + threadIdx.x;
    int p = atomicAdd(&cur[dst[e]], 1);
    eids[p] = e;
}

// ---------------- per-node input linears -> A planes ----------------
// A row layout (256): [a_so(32) | a_se(32) | a_vo_x | a_vo_y | a_vo_z | a_ve_x | a_ve_y | a_ve_z]
__global__ __launch_bounds__(256) void k_lin1(const float* __restrict__ st,
    const float* __restrict__ w_so, const float* __restrict__ w_se,
    const float* __restrict__ w_vo, const float* __restrict__ w_ve,
    float* __restrict__ A)
{
    __shared__ float wl[4][1024];
    __shared__ float sl[8][256];
    int t = threadIdx.x;
    for(int i=t;i<1024;i+=256){ wl[0][i]=w_so[i]; wl[1][i]=w_se[i]; wl[2][i]=w_vo[i]; wl[3][i]=w_ve[i]; }
    int n0 = blockIdx.x*8;
    for(int i=t;i<2048;i+=256){ int k=i>>8, c=i&255; sl[k][c]=st[(n0+k)*256+c]; }
    __syncthreads();
    for(int k=0;k<8;k++){
        float acc = 0.0f;
        if (t < 64){
            int m = t>>5, v = t&31;
            const float* w = wl[m];
            const float* s = &sl[k][m*32];
            #pragma unroll
            for(int u=0;u<32;u++) acc += s[u]*w[u*32+v];
        } else if (t < 160){
            int idx=t-64, i=idx>>5, v=idx&31;
            #pragma unroll
            for(int u=0;u<32;u++) acc += sl[k][64+u*3+i]*wl[2][u*32+v];
        } else {
            int idx=t-160, i=idx>>5, v=idx&31;
            #pragma unroll
            for(int u=0;u<32;u++) acc += sl[k][160+u*3+i]*wl[3][u*32+v];
        }
        A[(n0+k)*256 + t] = acc * INV_S32;
    }
}

// ---------------- radial MLP: emb(10) -> h(100, silu) -> W(NCOL), W stored bf16 ----------------
// 32 edges per block, 256 threads. rw2 staged in LDS in K-chunks of 20.
template<int NCOL>
__global__ __launch_bounds__(256) void k_radial(const float* __restrict__ emb,
    const float* __restrict__ rw1, const float* __restrict__ rw2,
    __hip_bfloat16* __restrict__ Wout)
{
    constexpr int CPT = NCOL/32;     // cols per thread
    __shared__ float s_rw1[1000];
    __shared__ float s_emb[320];
    __shared__ float s_h[32*101];    // pad 101: conflict-free across edges
    __shared__ float s_rw2[20*NCOL];
    int t = threadIdx.x;
    int ebase = blockIdx.x*32;
    for(int i=t;i<1000;i+=256) s_rw1[i] = rw1[i];
    for(int i=t;i<320;i+=256)  s_emb[i] = emb[ebase*10 + i];
    __syncthreads();
    {   // h
        int e = t & 31;
        int j0 = t >> 5;
        for(int j=j0;j<100;j+=8){
            float acc = 0.0f;
            #pragma unroll
            for(int i=0;i<10;i++) acc += s_emb[e*10+i]*s_rw1[i*100+j];
            acc *= INV_S10;
            s_h[e*101+j] = acc * sigmoid_f(acc);   // silu
        }
    }
    int cg = t & 31;     // col group -> cols cg*CPT .. +CPT-1
    int eg = t >> 5;     // edge group -> edges eg*4 .. +3
    float acc[4][CPT];
    #pragma unroll
    for(int a=0;a<4;a++)
        #pragma unroll
        for(int b=0;b<CPT;b++) acc[a][b]=0.0f;
    for(int kc=0;kc<5;kc++){
        __syncthreads();
        for(int i=t;i<20*NCOL;i+=256) s_rw2[i] = rw2[kc*20*NCOL + i];
        __syncthreads();
        for(int j=0;j<20;j++){
            float hv[4];
            #pragma unroll
            for(int a=0;a<4;a++) hv[a] = s_h[(eg*4+a)*101 + kc*20 + j];
            const float* r2 = &s_rw2[j*NCOL + cg*CPT];
            #pragma unroll
            for(int b=0;b<CPT;b++){
                float rv = r2[b];
                #pragma unroll
                for(int a=0;a<4;a++) acc[a][b] += hv[a]*rv;
            }
        }
    }
    #pragma unroll
    for(int a=0;a<4;a++){
        int e = ebase + eg*4 + a;
        #pragma unroll
        for(int b=0;b<CPT;b++)
            Wout[e*NCOL + cg*CPT + b] = __float2bfloat16(acc[a][b]*0.1f);  // /sqrt(100)
    }
}

// ---------------- per-node message aggregation (CSR gather, atomic-free) ----------------
// nbuf row (704): [n0o 64 | n0e 64 | n1o_x 96 | n1o_y 96 | n1o_z 96 | n1e_x 96 | n1e_y 96 | n1e_z 96]
__global__ __launch_bounds__(64) void k_aggregate(const float* __restrict__ A,
    const __hip_bfloat16* __restrict__ W, const float* __restrict__ y0,
    const float* __restrict__ y1, const int* __restrict__ eids,
    const int* __restrict__ off, const int* __restrict__ esrc,
    float* __restrict__ nbuf)
{
    int n = blockIdx.x;
    int l = threadIdx.x;
    int u = l & 31, half = l >> 5;
    int e0 = off[n], e1 = off[n+1];
    float a_n0o0=0.f, a_n0o1=0.f, a_n0e0=0.f, a_n0e1=0.f;
    float a1o[3][3] = {{0}}, a1e[3][3] = {{0}};
    for(int p=e0;p<e1;p++){
        int e = eids[p];
        int s = esrc[e];
        float cy0 = y0[e];
        float v1x=y1[e*3+0], v1y=y1[e*3+1], v1z=y1[e*3+2];
        const float* Ar = A + s*256;
        float aso=Ar[u],      ase=Ar[32+u];
        float vox=Ar[64+u],   voy=Ar[96+u],  voz=Ar[128+u];
        float vex=Ar[160+u],  vey=Ar[192+u], vez=Ar[224+u];
        const __hip_bfloat16* Wr = W + e*320;
        float w[10];
        #pragma unroll
        for(int sI=0;sI<10;sI++) w[sI] = __bfloat162float(Wr[sI*32+u]);
        float dve = (vex*v1x+vey*v1y+vez*v1z)*INV_SQ3;
        float dvo = (vox*v1x+voy*v1y+voz*v1z)*INV_SQ3;
        float cvex=(vey*v1z-vez*v1y)*INV_SQ2, cvey=(vez*v1x-vex*v1z)*INV_SQ2, cvez=(vex*v1y-vey*v1x)*INV_SQ2;
        float cvox=(voy*v1z-voz*v1y)*INV_SQ2, cvoy=(voz*v1x-vox*v1z)*INV_SQ2, cvoz=(vox*v1y-voy*v1x)*INV_SQ2;
        a_n0o0 += w[0]*aso*cy0;
        a_n0o1 += w[1]*dve;
        a_n0e0 += w[2]*ase*cy0;
        a_n0e1 += w[3]*dvo;
        a1o[0][0]+=w[4]*ase*v1x; a1o[0][1]+=w[4]*ase*v1y; a1o[0][2]+=w[4]*ase*v1z;
        a1o[1][0]+=w[5]*vox*cy0; a1o[1][1]+=w[5]*voy*cy0; a1o[1][2]+=w[5]*voz*cy0;
        a1o[2][0]+=w[6]*cvex;    a1o[2][1]+=w[6]*cvey;    a1o[2][2]+=w[6]*cvez;
        a1e[0][0]+=w[7]*aso*v1x; a1e[0][1]+=w[7]*aso*v1y; a1e[0][2]+=w[7]*aso*v1z;
        a1e[1][0]+=w[8]*cvox;    a1e[1][1]+=w[8]*cvoy;    a1e[1][2]+=w[8]*cvoz;
        a1e[2][0]+=w[9]*vex*cy0; a1e[2][1]+=w[9]*vey*cy0; a1e[2][2]+=w[9]*vez*cy0;
    }
    float s0 = INV_SQ2*0.25f;   // m0 concat scale * seg 1/sqrt(16)
    float s1 = INV_SQ3*0.25f;   // m1 concat scale * seg
    float* nb = nbuf + n*704;
    if (half==0){
        nb[u]      = a_n0o0*s0;
        nb[32+u]   = a_n0o1*s0;
        nb[64+u]   = a_n0e0*s0;
        nb[96+u]   = a_n0e1*s0;
        #pragma unroll
        for(int sp=0;sp<3;sp++)
            #pragma unroll
            for(int i=0;i<3;i++)
                nb[128 + i*96 + sp*32 + u] = a1o[sp][i]*s1;
    } else {
        #pragma unroll
        for(int sp=0;sp<3;sp++)
            #pragma unroll
            for(int i=0;i<3;i++)
                nb[416 + i*96 + sp*32 + u] = a1e[sp][i]*s1;
    }
}

// ---------------- node update: skip + aggregated linears + nonlinearity/gating ----------------
__global__ __launch_bounds__(256) void k_update(const float* __restrict__ st,
    const float* __restrict__ nbuf,
    const float* __restrict__ wsso, const float* __restrict__ wsse,
    const float* __restrict__ wsvo, const float* __restrict__ wsve,
    const float* __restrict__ w2so, const float* __restrict__ w2se,
    const float* __restrict__ w2vo, const float* __restrict__ w2ve,
    float* __restrict__ stnew)
{
    int n = blockIdx.x, t = threadIdx.x;
    __shared__ float g[64];
    const float* sr = st + n*256;
    const float* nb = nbuf + n*704;
    if (t < 96){
        float acc1=0.f, acc2=0.f;
        #pragma unroll
        for(int u=0;u<32;u++) acc1 += sr[32+u]*wsse[u*96+t];
        for(int q=0;q<64;q++) acc2 += nb[64+q]*w2se[q*96+t];
        float o = C_S_F*INV_S32*acc1 + C_X_F*0.125f*acc2;
        if (t < 32) stnew[n*256 + 32 + t] = o*sigmoid_f(o);   // silu
        else        g[t-32] = sigmoid_f(o);
    }
    __syncthreads();
    if (t < 32){
        float acc1=0.f, acc2=0.f;
        #pragma unroll
        for(int u=0;u<32;u++) acc1 += sr[u]*wsso[u*32+t];
        for(int q=0;q<64;q++) acc2 += nb[q]*w2so[q*32+t];
        stnew[n*256+t] = tanhf(C_S_F*INV_S32*acc1 + C_X_F*0.125f*acc2);
    } else if (t >= 64 && t < 160){
        int idx=t-64, i=idx>>5, v=idx&31;
        float acc1=0.f, acc2=0.f;
        #pragma unroll
        for(int u=0;u<32;u++) acc1 += sr[64+u*3+i]*wsvo[u*32+v];
        for(int q=0;q<96;q++) acc2 += nb[128+i*96+q]*w2vo[q*32+v];
        stnew[n*256+64+v*3+i] = (C_S_F*INV_S32*acc1 + C_X_F*INV_S96*acc2)*g[v];
    } else if (t >= 160){
        int idx=t-160, i=idx>>5, v=idx&31;
        float acc1=0.f, acc2=0.f;
        #pragma unroll
        for(int u=0;u<32;u++) acc1 += sr[160+u*3+i]*wsve[u*32+v];
        for(int q=0;q<96;q++) acc2 += nb[416+i*96+q]*w2ve[q*32+v];
        stnew[n*256+160+v*3+i] = (C_S_F*INV_S32*acc1 + C_X_F*INV_S96*acc2)*g[32+v];
    }
}

// ---------------- final: node linears -> afin planes [a_se | a_vo_x | a_vo_y | a_vo_z] ----------------
__global__ __launch_bounds__(128) void k_flin(const float* __restrict__ st,
    const float* __restrict__ wse, const float* __restrict__ wvo, float* __restrict__ afin)
{
    int n = blockIdx.x, t = threadIdx.x;
    const float* sr = st + n*256;
    float acc = 0.0f;
    if (t < 32){
        #pragma unroll
        for(int u=0;u<32;u++) acc += sr[32+u]*wse[u*32+t];
    } else {
        int idx=t-32, i=idx>>5, v=idx&31;
        #pragma unroll
        for(int u=0;u<32;u++) acc += sr[64+u*3+i]*wvo[u*32+v];
    }
    afin[n*128 + t] = acc * INV_S32;
}

// ---------------- final aggregate + readout + per-graph reduction ----------------
__global__ __launch_bounds__(64) void k_fagg(const float* __restrict__ afin,
    const __hip_bfloat16* __restrict__ Wf, const float* __restrict__ st,
    const float* __restrict__ y0, const float* __restrict__ y1,
    const int* __restrict__ eids, const int* __restrict__ off, const int* __restrict__ esrc,
    const float* __restrict__ fsc_se, const float* __restrict__ flin2,
    const int* __restrict__ batch, float* __restrict__ out)
{
    int n = blockIdx.x, l = threadIdx.x, u = l & 31;
    int e0 = off[n], e1 = off[n+1];
    float ca=0.f, cb=0.f;
    for(int p=e0;p<e1;p++){
        int e = eids[p];
        int s = esrc[e];
        float cy0 = y0[e];
        float v1x=y1[e*3+0], v1y=y1[e*3+1], v1z=y1[e*3+2];
        const float* Ar = afin + s*128;
        float ase = Ar[u];
        float vx=Ar[32+u], vy=Ar[64+u], vz=Ar[96+u];
        float w0 = __bfloat162float(Wf[e*64 + u]);
        float w1 = __bfloat162float(Wf[e*64 + 32 + u]);
        ca += w0*ase*cy0;
        cb += w1*(vx*v1x+vy*v1y+vz*v1z)*INV_SQ3;
    }
    float f = INV_SQ2*0.25f;   // m0e concat scale * seg
    // each u computed by 2 lanes (both halves) -> 0.5 dedup factor before wave sum
    float val = 0.5f*C_X_F*0.125f*(ca*f*flin2[u] + cb*f*flin2[32+u])
              + 0.5f*C_S_F*INV_S32*(st[n*256+32+u]*fsc_se[u]);
    #pragma unroll
    for(int o=32;o>0;o>>=1) val += __shfl_xor(val, o);
    if (l==0) atomicAdd(&out[batch[n]], val*OUT_S);
}

// ---------------- host ----------------
extern "C" void kernel_launch(void* const* d_in, const int* in_sizes, int n_in,
                              void* d_out, int out_size, void* d_ws, size_t ws_size,
                              hipStream_t stream)
{
    const float* x        = (const float*)d_in[0];
    const float* edge_vec = (const float*)d_in[1];
    const float* lin1_so  = (const float*)d_in[2];
    const float* lin1_se  = (const float*)d_in[3];
    const float* lin1_vo  = (const float*)d_in[4];
    const float* lin1_ve  = (const float*)d_in[5];
    const float* sc_so    = (const float*)d_in[6];
    const float* sc_se    = (const float*)d_in[7];
    const float* sc_vo    = (const float*)d_in[8];
    const float* sc_ve    = (const float*)d_in[9];
    const float* rad_w1   = (const float*)d_in[10];
    const float* rad_w2   = (const float*)d_in[11];
    const float* lin2_so  = (const float*)d_in[12];
    const float* lin2_se  = (const float*)d_in[13];
    const float* lin2_vo  = (const float*)d_in[14];
    const float* lin2_ve  = (const float*)d_in[15];
    const float* flin1_se = (const float*)d_in[16];
    const float* flin1_vo = (const float*)d_in[17];
    const float* fsc_se   = (const float*)d_in[18];
    const float* frad_w1  = (const float*)d_in[19];
    const float* frad_w2  = (const float*)d_in[20];
    const float* flin2    = (const float*)d_in[21];
    const int*   esrc     = (const int*)d_in[22];
    const int*   edst     = (const int*)d_in[23];
    const int*   batch    = (const int*)d_in[24];
    float* out = (float*)d_out;

    uint8_t* ws = (uint8_t*)d_ws;
    size_t off = 0;
    auto alloc = [&](size_t bytes)->void* {
        void* p = ws + off;
        off += (bytes + 255) & ~(size_t)255;
        return p;
    };
    float* y0    = (float*)alloc((size_t)EE*4);
    float* y1    = (float*)alloc((size_t)EE*12);
    float* emb   = (float*)alloc((size_t)EE*40);
    int*   cnt   = (int*)  alloc((size_t)NN*4);
    int*   csro  = (int*)  alloc((size_t)(NN+1)*4);
    int*   cur   = (int*)  alloc((size_t)NN*4);
    int*   eids  = (int*)  alloc((size_t)EE*4);
    float* A     = (float*)alloc((size_t)NN*256*4);
    __hip_bfloat16* W = (__hip_bfloat16*)alloc((size_t)EE*320*2);
    float* nbuf  = (float*)alloc((size_t)NN*704*4);
    float* st0   = (float*)alloc((size_t)NN*256*4);
    float* st1   = (float*)alloc((size_t)NN*256*4);
    float* afin  = (float*)alloc((size_t)NN*128*4);

    hipMemsetAsync(out, 0, (size_t)out_size*sizeof(float), stream);
    hipMemsetAsync(cnt, 0, (size_t)NN*4, stream);

    k_geom   <<<EE/256, 256, 0, stream>>>(edge_vec, y0, y1, emb);
    k_count  <<<EE/256, 256, 0, stream>>>(edst, cnt);
    k_scan   <<<1, 1024, 0, stream>>>(cnt, csro, cur);
    k_scatter<<<EE/256, 256, 0, stream>>>(edst, cur, eids);

    const float* st_in = x;
    float* bufs[2] = { st0, st1 };
    for (int l=0; l<3; l++){
        k_lin1<<<NN/8, 256, 0, stream>>>(st_in,
            lin1_so + l*1024, lin1_se + l*1024, lin1_vo + l*1024, lin1_ve + l*1024, A);
        k_radial<320><<<EE/32, 256, 0, stream>>>(emb, rad_w1 + l*1000, rad_w2 + l*32000, W);
        k_aggregate<<<NN, 64, 0, stream>>>(A, W, y0, y1, eids, csro, esrc, nbuf);
        float* st_out = bufs[l & 1];
        k_update<<<NN, 256, 0, stream>>>(st_in, nbuf,
            sc_so + l*1024, sc_se + l*3072, sc_vo + l*1024, sc_ve + l*1024,
            lin2_so + l*2048, lin2_se + l*6144, lin2_vo + l*3072, lin2_ve + l*3072,
            st_out);
        st_in = st_out;
    }
    k_flin<<<NN, 128, 0, stream>>>(st_in, flin1_se, flin1_vo, afin);
    k_radial<64><<<EE/32, 256, 0, stream>>>(emb, frad_w1, frad_w2, W);
    k_fagg<<<NN, 64, 0, stream>>>(afin, W, st_in, y0, y1, eids, csro, esrc,
                                  fsc_se, flin2, batch, out);
}

// Round 2
// 1467.431 us; speedup vs baseline: 7.0727x; 7.0727x over previous
//
#include <hip/hip_runtime.h>
#include <hip/hip_bf16.h>
#include <math.h>
#include <stdint.h>

#define NN 8192
#define EE 131072

#define PI_F     3.14159265358979323846f
#define SQRT3_F  1.7320508075688772f
#define INV_SQ2  0.7071067811865476f
#define INV_SQ3  0.5773502691896258f
#define INV_S32  0.17677669529663687f
#define INV_S96  0.10206207261596575f
#define INV_S10  0.31622776601683794f
#define C_S_F    0.3826834323650898f
#define C_X_F    0.9238795325112867f
#define EMB_S    2.8234621965789795f   /* sqrt(10)/1.12 */
#define OUT_S    0.044194173824159216f /* 1/sqrt(512)   */

__device__ __forceinline__ float sigmoid_f(float x){ return 1.0f/(1.0f+__expf(-x)); }

// ---------------- edge geometry: r, cutoff, y1, radial basis ----------------
__global__ __launch_bounds__(256) void k_geom(const float* __restrict__ ev,
    float* __restrict__ y0, float* __restrict__ y1, float* __restrict__ emb)
{
    int e = blockIdx.x*256 + threadIdx.x;
    float vx=ev[e*3+0], vy=ev[e*3+1], vz=ev[e*3+2];
    float r = sqrtf(vx*vx+vy*vy+vz*vz);
    float uu = 0.5f*r - 2.0f;                 // u = 2*(r/4 - 1)
    float cut;
    if (uu > 0.0f)       cut = 0.0f;
    else if (uu < -1.0f) cut = 1.0f;
    else                 cut = 0.5f*(1.0f - cosf(PI_F*uu));
    y0[e] = cut;
    float s = SQRT3_F*cut/(r + 1e-12f);
    y1[e*3+0]=vx*s; y1[e*3+1]=vy*s; y1[e*3+2]=vz*s;
    #pragma unroll
    for(int b=0;b<10;b++){
        float d = r*2.25f - (float)b;         // (r - b*4/9)/(4/9)
        emb[e*10+b] = __expf(-d*d)*EMB_S;
    }
}

// ---------------- CSR build (sort edges by dst) ----------------
__global__ __launch_bounds__(256) void k_count(const int* __restrict__ dst, int* __restrict__ cnt)
{
    int e = blockIdx.x*256 + threadIdx.x;
    atomicAdd(&cnt[dst[e]], 1);
}

__global__ __launch_bounds__(1024) void k_scan(const int* __restrict__ cnt,
    int* __restrict__ off, int* __restrict__ cur)
{
    __shared__ int partial[1024];
    int t = threadIdx.x;
    int base = t*8;
    int local[8];
    int s = 0;
    #pragma unroll
    for(int i=0;i<8;i++){ local[i]=s; s += cnt[base+i]; }
    partial[t] = s;
    __syncthreads();
    for(int d=1; d<1024; d<<=1){
        int v = (t>=d) ? partial[t-d] : 0;
        __syncthreads();
        partial[t] += v;
        __syncthreads();
    }
    int pref = (t>0) ? partial[t-1] : 0;
    #pragma unroll
    for(int i=0;i<8;i++){
        int o = pref + local[i];
        off[base+i] = o; cur[base+i] = o;
    }
    if (t==1023) off[NN] = partial[1023];
}

__global__ __launch_bounds__(256) void k_scatter(const int* __restrict__ dst,
    int* __restrict__ cur, int* __restrict__ eids)
{
    int e = blockIdx.x*256 + threadIdx.x;
    int p = atomicAdd(&cur[dst[e]], 1);
    eids[p] = e;
}

// ---------------- per-node input linears -> A planes ----------------
// A row layout (256): [a_so(32) | a_se(32) | a_vo_x | a_vo_y | a_vo_z | a_ve_x | a_ve_y | a_ve_z]
__global__ __launch_bounds__(256) void k_lin1(const float* __restrict__ st,
    const float* __restrict__ w_so, const float* __restrict__ w_se,
    const float* __restrict__ w_vo, const float* __restrict__ w_ve,
    float* __restrict__ A)
{
    __shared__ float wl[4][1024];
    __shared__ float sl[8][256];
    int t = threadIdx.x;
    for(int i=t;i<1024;i+=256){ wl[0][i]=w_so[i]; wl[1][i]=w_se[i]; wl[2][i]=w_vo[i]; wl[3][i]=w_ve[i]; }
    int n0 = blockIdx.x*8;
    for(int i=t;i<2048;i+=256){ int k=i>>8, c=i&255; sl[k][c]=st[(n0+k)*256+c]; }
    __syncthreads();
    for(int k=0;k<8;k++){
        float acc = 0.0f;
        if (t < 64){
            int m = t>>5, v = t&31;
            const float* w = wl[m];
            const float* s = &sl[k][m*32];
            #pragma unroll
            for(int u=0;u<32;u++) acc += s[u]*w[u*32+v];
        } else if (t < 160){
            int idx=t-64, i=idx>>5, v=idx&31;
            #pragma unroll
            for(int u=0;u<32;u++) acc += sl[k][64+u*3+i]*wl[2][u*32+v];
        } else {
            int idx=t-160, i=idx>>5, v=idx&31;
            #pragma unroll
            for(int u=0;u<32;u++) acc += sl[k][160+u*3+i]*wl[3][u*32+v];
        }
        A[(n0+k)*256 + t] = acc * INV_S32;
    }
}

// ---------------- radial MLP: emb(10) -> h(100, silu) -> W(NCOL), W stored bf16 ----------------
// 32 edges per block, 256 threads. rw2 read straight from global (L2-resident, 128 KB).
// Unroll is capped and VGPRs bounded: round-1 version spilled (VGPR=256, 7.3 GB scratch traffic).
template<int NCOL>
__global__ __launch_bounds__(256, 4) void k_radial(const float* __restrict__ emb,
    const float* __restrict__ rw1, const float* __restrict__ rw2,
    __hip_bfloat16* __restrict__ Wout)
{
    constexpr int CPT = NCOL/32;     // cols per thread (10 or 2)
    __shared__ float s_rw1[1000];
    __shared__ float s_emb[320];
    __shared__ float s_h[32*101];    // stride 101: conflict-free writes
    int t = threadIdx.x;
    int ebase = blockIdx.x*32;
    for(int i=t;i<1000;i+=256) s_rw1[i] = rw1[i];
    for(int i=t;i<320;i+=256)  s_emb[i] = emb[ebase*10 + i];
    __syncthreads();
    {   // h = silu(emb @ rw1 / sqrt(10))
        int e = t & 31;
        int j0 = t >> 5;
        for(int j=j0;j<100;j+=8){
            float acc = 0.0f;
            #pragma unroll
            for(int i=0;i<10;i++) acc += s_emb[e*10+i]*s_rw1[i*100+j];
            acc *= INV_S10;
            s_h[e*101+j] = acc * sigmoid_f(acc);   // silu
        }
    }
    __syncthreads();
    int cg = t & 31;     // col group -> cols cg*CPT .. +CPT-1
    int eg = t >> 5;     // edge group -> edges eg*4 .. +3
    float acc[4][CPT];
    #pragma unroll
    for(int a=0;a<4;a++)
        #pragma unroll
        for(int b=0;b<CPT;b++) acc[a][b]=0.0f;
    const float* r2base = rw2 + cg*CPT;
    #pragma unroll 2
    for(int j=0;j<100;j++){
        float hv0 = s_h[(eg*4+0)*101 + j];
        float hv1 = s_h[(eg*4+1)*101 + j];
        float hv2 = s_h[(eg*4+2)*101 + j];
        float hv3 = s_h[(eg*4+3)*101 + j];
        const float* r2 = r2base + j*NCOL;
        #pragma unroll
        for(int b=0;b<CPT;b++){
            float rv = r2[b];
            acc[0][b] += hv0*rv;
            acc[1][b] += hv1*rv;
            acc[2][b] += hv2*rv;
            acc[3][b] += hv3*rv;
        }
    }
    #pragma unroll
    for(int a=0;a<4;a++){
        int e = ebase + eg*4 + a;
        #pragma unroll
        for(int b=0;b<CPT;b++)
            Wout[e*NCOL + cg*CPT + b] = __float2bfloat16(acc[a][b]*0.1f);  // /sqrt(100)
    }
}

// ---------------- per-node message aggregation (CSR gather, atomic-free) ----------------
// nbuf row (704): [n0o 64 | n0e 64 | n1o_x 96 | n1o_y 96 | n1o_z 96 | n1e_x 96 | n1e_y 96 | n1e_z 96]
__global__ __launch_bounds__(64) void k_aggregate(const float* __restrict__ A,
    const __hip_bfloat16* __restrict__ W, const float* __restrict__ y0,
    const float* __restrict__ y1, const int* __restrict__ eids,
    const int* __restrict__ off, const int* __restrict__ esrc,
    float* __restrict__ nbuf)
{
    int n = blockIdx.x;
    int l = threadIdx.x;
    int u = l & 31, half = l >> 5;
    int e0 = off[n], e1 = off[n+1];
    float a_n0o0=0.f, a_n0o1=0.f, a_n0e0=0.f, a_n0e1=0.f;
    float a1o[3][3] = {{0}}, a1e[3][3] = {{0}};
    for(int p=e0;p<e1;p++){
        int e = eids[p];
        int s = esrc[e];
        float cy0 = y0[e];
        float v1x=y1[e*3+0], v1y=y1[e*3+1], v1z=y1[e*3+2];
        const float* Ar = A + s*256;
        float aso=Ar[u],      ase=Ar[32+u];
        float vox=Ar[64+u],   voy=Ar[96+u],  voz=Ar[128+u];
        float vex=Ar[160+u],  vey=Ar[192+u], vez=Ar[224+u];
        const __hip_bfloat16* Wr = W + e*320;
        float w[10];
        #pragma unroll
        for(int sI=0;sI<10;sI++) w[sI] = __bfloat162float(Wr[sI*32+u]);
        float dve = (vex*v1x+vey*v1y+vez*v1z)*INV_SQ3;
        float dvo = (vox*v1x+voy*v1y+voz*v1z)*INV_SQ3;
        float cvex=(vey*v1z-vez*v1y)*INV_SQ2, cvey=(vez*v1x-vex*v1z)*INV_SQ2, cvez=(vex*v1y-vey*v1x)*INV_SQ2;
        float cvox=(voy*v1z-voz*v1y)*INV_SQ2, cvoy=(voz*v1x-vox*v1z)*INV_SQ2, cvoz=(vox*v1y-voy*v1x)*INV_SQ2;
        a_n0o0 += w[0]*aso*cy0;
        a_n0o1 += w[1]*dve;
        a_n0e0 += w[2]*ase*cy0;
        a_n0e1 += w[3]*dvo;
        a1o[0][0]+=w[4]*ase*v1x; a1o[0][1]+=w[4]*ase*v1y; a1o[0][2]+=w[4]*ase*v1z;
        a1o[1][0]+=w[5]*vox*cy0; a1o[1][1]+=w[5]*voy*cy0; a1o[1][2]+=w[5]*voz*cy0;
        a1o[2][0]+=w[6]*cvex;    a1o[2][1]+=w[6]*cvey;    a1o[2][2]+=w[6]*cvez;
        a1e[0][0]+=w[7]*aso*v1x; a1e[0][1]+=w[7]*aso*v1y; a1e[0][2]+=w[7]*aso*v1z;
        a1e[1][0]+=w[8]*cvox;    a1e[1][1]+=w[8]*cvoy;    a1e[1][2]+=w[8]*cvoz;
        a1e[2][0]+=w[9]*vex*cy0; a1e[2][1]+=w[9]*vey*cy0; a1e[2][2]+=w[9]*vez*cy0;
    }
    float s0 = INV_SQ2*0.25f;   // m0 concat scale * seg 1/sqrt(16)
    float s1 = INV_SQ3*0.25f;   // m1 concat scale * seg
    float* nb = nbuf + n*704;
    if (half==0){
        nb[u]      = a_n0o0*s0;
        nb[32+u]   = a_n0o1*s0;
        nb[64+u]   = a_n0e0*s0;
        nb[96+u]   = a_n0e1*s0;
        #pragma unroll
        for(int sp=0;sp<3;sp++)
            #pragma unroll
            for(int i=0;i<3;i++)
                nb[128 + i*96 + sp*32 + u] = a1o[sp][i]*s1;
    } else {
        #pragma unroll
        for(int sp=0;sp<3;sp++)
            #pragma unroll
            for(int i=0;i<3;i++)
                nb[416 + i*96 + sp*32 + u] = a1e[sp][i]*s1;
    }
}

// ---------------- node update: skip + aggregated linears + nonlinearity/gating ----------------
__global__ __launch_bounds__(256) void k_update(const float* __restrict__ st,
    const float* __restrict__ nbuf,
    const float* __restrict__ wsso, const float* __restrict__ wsse,
    const float* __restrict__ wsvo, const float* __restrict__ wsve,
    const float* __restrict__ w2so, const float* __restrict__ w2se,
    const float* __restrict__ w2vo, const float* __restrict__ w2ve,
    float* __restrict__ stnew)
{
    int n = blockIdx.x, t = threadIdx.x;
    __shared__ float g[64];
    const float* sr = st + n*256;
    const float* nb = nbuf + n*704;
    if (t < 96){
        float acc1=0.f, acc2=0.f;
        #pragma unroll
        for(int u=0;u<32;u++) acc1 += sr[32+u]*wsse[u*96+t];
        for(int q=0;q<64;q++) acc2 += nb[64+q]*w2se[q*96+t];
        float o = C_S_F*INV_S32*acc1 + C_X_F*0.125f*acc2;
        if (t < 32) stnew[n*256 + 32 + t] = o*sigmoid_f(o);   // silu
        else        g[t-32] = sigmoid_f(o);
    }
    __syncthreads();
    if (t < 32){
        float acc1=0.f, acc2=0.f;
        #pragma unroll
        for(int u=0;u<32;u++) acc1 += sr[u]*wsso[u*32+t];
        for(int q=0;q<64;q++) acc2 += nb[q]*w2so[q*32+t];
        stnew[n*256+t] = tanhf(C_S_F*INV_S32*acc1 + C_X_F*0.125f*acc2);
    } else if (t >= 64 && t < 160){
        int idx=t-64, i=idx>>5, v=idx&31;
        float acc1=0.f, acc2=0.f;
        #pragma unroll
        for(int u=0;u<32;u++) acc1 += sr[64+u*3+i]*wsvo[u*32+v];
        for(int q=0;q<96;q++) acc2 += nb[128+i*96+q]*w2vo[q*32+v];
        stnew[n*256+64+v*3+i] = (C_S_F*INV_S32*acc1 + C_X_F*INV_S96*acc2)*g[v];
    } else if (t >= 160){
        int idx=t-160, i=idx>>5, v=idx&31;
        float acc1=0.f, acc2=0.f;
        #pragma unroll
        for(int u=0;u<32;u++) acc1 += sr[160+u*3+i]*wsve[u*32+v];
        for(int q=0;q<96;q++) acc2 += nb[416+i*96+q]*w2ve[q*32+v];
        stnew[n*256+160+v*3+i] = (C_S_F*INV_S32*acc1 + C_X_F*INV_S96*acc2)*g[32+v];
    }
}

// ---------------- final: node linears -> afin planes [a_se | a_vo_x | a_vo_y | a_vo_z] ----------------
__global__ __launch_bounds__(128) void k_flin(const float* __restrict__ st,
    const float* __restrict__ wse, const float* __restrict__ wvo, float* __restrict__ afin)
{
    int n = blockIdx.x, t = threadIdx.x;
    const float* sr = st + n*256;
    float acc = 0.0f;
    if (t < 32){
        #pragma unroll
        for(int u=0;u<32;u++) acc += sr[32+u]*wse[u*32+t];
    } else {
        int idx=t-32, i=idx>>5, v=idx&31;
        #pragma unroll
        for(int u=0;u<32;u++) acc += sr[64+u*3+i]*wvo[u*32+v];
    }
    afin[n*128 + t] = acc * INV_S32;
}

// ---------------- final aggregate + readout + per-graph reduction ----------------
__global__ __launch_bounds__(64) void k_fagg(const float* __restrict__ afin,
    const __hip_bfloat16* __restrict__ Wf, const float* __restrict__ st,
    const float* __restrict__ y0, const float* __restrict__ y1,
    const int* __restrict__ eids, const int* __restrict__ off, const int* __restrict__ esrc,
    const float* __restrict__ fsc_se, const float* __restrict__ flin2,
    const int* __restrict__ batch, float* __restrict__ out)
{
    int n = blockIdx.x, l = threadIdx.x, u = l & 31;
    int e0 = off[n], e1 = off[n+1];
    float ca=0.f, cb=0.f;
    for(int p=e0;p<e1;p++){
        int e = eids[p];
        int s = esrc[e];
        float cy0 = y0[e];
        float v1x=y1[e*3+0], v1y=y1[e*3+1], v1z=y1[e*3+2];
        const float* Ar = afin + s*128;
        float ase = Ar[u];
        float vx=Ar[32+u], vy=Ar[64+u], vz=Ar[96+u];
        float w0 = __bfloat162float(Wf[e*64 + u]);
        float w1 = __bfloat162float(Wf[e*64 + 32 + u]);
        ca += w0*ase*cy0;
        cb += w1*(vx*v1x+vy*v1y+vz*v1z)*INV_SQ3;
    }
    float f = INV_SQ2*0.25f;   // m0e concat scale * seg
    // each u computed by 2 lanes (both halves) -> 0.5 dedup factor before wave sum
    float val = 0.5f*C_X_F*0.125f*(ca*f*flin2[u] + cb*f*flin2[32+u])
              + 0.5f*C_S_F*INV_S32*(st[n*256+32+u]*fsc_se[u]);
    #pragma unroll
    for(int o=32;o>0;o>>=1) val += __shfl_xor(val, o);
    if (l==0) atomicAdd(&out[batch[n]], val*OUT_S);
}

// ---------------- host ----------------
extern "C" void kernel_launch(void* const* d_in, const int* in_sizes, int n_in,
                              void* d_out, int out_size, void* d_ws, size_t ws_size,
                              hipStream_t stream)
{
    const float* x        = (const float*)d_in[0];
    const float* edge_vec = (const float*)d_in[1];
    const float* lin1_so  = (const float*)d_in[2];
    const float* lin1_se  = (const float*)d_in[3];
    const float* lin1_vo  = (const float*)d_in[4];
    const float* lin1_ve  = (const float*)d_in[5];
    const float* sc_so    = (const float*)d_in[6];
    const float* sc_se    = (const float*)d_in[7];
    const float* sc_vo    = (const float*)d_in[8];
    const float* sc_ve    = (const float*)d_in[9];
    const float* rad_w1   = (const float*)d_in[10];
    const float* rad_w2   = (const float*)d_in[11];
    const float* lin2_so  = (const float*)d_in[12];
    const float* lin2_se  = (const float*)d_in[13];
    const float* lin2_vo  = (const float*)d_in[14];
    const float* lin2_ve  = (const float*)d_in[15];
    const float* flin1_se = (const float*)d_in[16];
    const float* flin1_vo = (const float*)d_in[17];
    const float* fsc_se   = (const float*)d_in[18];
    const float* frad_w1  = (const float*)d_in[19];
    const float* frad_w2  = (const float*)d_in[20];
    const float* flin2    = (const float*)d_in[21];
    const int*   esrc     = (const int*)d_in[22];
    const int*   edst     = (const int*)d_in[23];
    const int*   batch    = (const int*)d_in[24];
    float* out = (float*)d_out;

    uint8_t* ws = (uint8_t*)d_ws;
    size_t off = 0;
    auto alloc = [&](size_t bytes)->void* {
        void* p = ws + off;
        off += (bytes + 255) & ~(size_t)255;
        return p;
    };
    float* y0    = (float*)alloc((size_t)EE*4);
    float* y1    = (float*)alloc((size_t)EE*12);
    float* emb   = (float*)alloc((size_t)EE*40);
    int*   cnt   = (int*)  alloc((size_t)NN*4);
    int*   csro  = (int*)  alloc((size_t)(NN+1)*4);
    int*   cur   = (int*)  alloc((size_t)NN*4);
    int*   eids  = (int*)  alloc((size_t)EE*4);
    float* A     = (float*)alloc((size_t)NN*256*4);
    __hip_bfloat16* W = (__hip_bfloat16*)alloc((size_t)EE*320*2);
    float* nbuf  = (float*)alloc((size_t)NN*704*4);
    float* st0   = (float*)alloc((size_t)NN*256*4);
    float* st1   = (float*)alloc((size_t)NN*256*4);
    float* afin  = (float*)alloc((size_t)NN*128*4);

    hipMemsetAsync(out, 0, (size_t)out_size*sizeof(float), stream);
    hipMemsetAsync(cnt, 0, (size_t)NN*4, stream);

    k_geom   <<<EE/256, 256, 0, stream>>>(edge_vec, y0, y1, emb);
    k_count  <<<EE/256, 256, 0, stream>>>(edst, cnt);
    k_scan   <<<1, 1024, 0, stream>>>(cnt, csro, cur);
    k_scatter<<<EE/256, 256, 0, stream>>>(edst, cur, eids);

    const float* st_in = x;
    float* bufs[2] = { st0, st1 };
    for (int l=0; l<3; l++){
        k_lin1<<<NN/8, 256, 0, stream>>>(st_in,
            lin1_so + l*1024, lin1_se + l*1024, lin1_vo + l*1024, lin1_ve + l*1024, A);
        k_radial<320><<<EE/32, 256, 0, stream>>>(emb, rad_w1 + l*1000, rad_w2 + l*32000, W);
        k_aggregate<<<NN, 64, 0, stream>>>(A, W, y0, y1, eids, csro, esrc, nbuf);
        float* st_out = bufs[l & 1];
        k_update<<<NN, 256, 0, stream>>>(st_in, nbuf,
            sc_so + l*1024, sc_se + l*3072, sc_vo + l*1024, sc_ve + l*1024,
            lin2_so + l*2048, lin2_se + l*6144, lin2_vo + l*3072, lin2_ve + l*3072,
            st_out);
        st_in = st_out;
    }
    k_flin<<<NN, 128, 0, stream>>>(st_in, flin1_se, flin1_vo, afin);
    k_radial<64><<<EE/32, 256, 0, stream>>>(emb, frad_w1, frad_w2, W);
    k_fagg<<<NN, 64, 0, stream>>>(afin, W, st_in, y0, y1, eids, csro, esrc,
                                  fsc_se, flin2, batch, out);
}

// Round 3
// 849.322 us; speedup vs baseline: 12.2199x; 1.7278x over previous
//
#include <hip/hip_runtime.h>
#include <hip/hip_bf16.h>
#include <math.h>
#include <stdint.h>

#define NN 8192
#define EE 131072

#define PI_F     3.14159265358979323846f
#define SQRT3_F  1.7320508075688772f
#define INV_SQ2  0.7071067811865476f
#define INV_SQ3  0.5773502691896258f
#define INV_S32  0.17677669529663687f
#define INV_S96  0.10206207261596575f
#define INV_S10  0.31622776601683794f
#define C_S_F    0.3826834323650898f
#define C_X_F    0.9238795325112867f
#define EMB_S    2.8234621965789795f   /* sqrt(10)/1.12 */
#define OUT_S    0.044194173824159216f /* 1/sqrt(512)   */

typedef unsigned int uint;
typedef unsigned short ushort;
typedef __attribute__((ext_vector_type(8))) short short8;
typedef __attribute__((ext_vector_type(4))) float float4v;

__device__ __forceinline__ float sigmoid_f(float x){ return 1.0f/(1.0f+__expf(-x)); }
__device__ __forceinline__ ushort f2bf(float f){
    uint u = __float_as_uint(f);
    u = (u + 0x7fffu + ((u>>16)&1u)) >> 16;
    return (ushort)u;
}
__device__ __forceinline__ float bf2f(ushort w){ return __uint_as_float(((uint)w)<<16); }

// ---------------- edge geometry: r, cutoff, y1, radial basis ----------------
__global__ __launch_bounds__(256) void k_geom(const float* __restrict__ ev,
    float* __restrict__ y0, float* __restrict__ y1, float* __restrict__ emb)
{
    int e = blockIdx.x*256 + threadIdx.x;
    float vx=ev[e*3+0], vy=ev[e*3+1], vz=ev[e*3+2];
    float r = sqrtf(vx*vx+vy*vy+vz*vz);
    float uu = 0.5f*r - 2.0f;                 // u = 2*(r/4 - 1)
    float cut;
    if (uu > 0.0f)       cut = 0.0f;
    else if (uu < -1.0f) cut = 1.0f;
    else                 cut = 0.5f*(1.0f - cosf(PI_F*uu));
    y0[e] = cut;
    float s = SQRT3_F*cut/(r + 1e-12f);
    y1[e*3+0]=vx*s; y1[e*3+1]=vy*s; y1[e*3+2]=vz*s;
    #pragma unroll
    for(int b=0;b<10;b++){
        float d = r*2.25f - (float)b;         // (r - b*4/9)/(4/9)
        emb[e*10+b] = __expf(-d*d)*EMB_S;
    }
}

// ---------------- CSR build (sort edges by dst) ----------------
__global__ __launch_bounds__(256) void k_count(const int* __restrict__ dst, int* __restrict__ cnt)
{
    int e = blockIdx.x*256 + threadIdx.x;
    atomicAdd(&cnt[dst[e]], 1);
}

__global__ __launch_bounds__(1024) void k_scan(const int* __restrict__ cnt,
    int* __restrict__ off, int* __restrict__ cur)
{
    __shared__ int partial[1024];
    int t = threadIdx.x;
    int base = t*8;
    int local[8];
    int s = 0;
    #pragma unroll
    for(int i=0;i<8;i++){ local[i]=s; s += cnt[base+i]; }
    partial[t] = s;
    __syncthreads();
    for(int d=1; d<1024; d<<=1){
        int v = (t>=d) ? partial[t-d] : 0;
        __syncthreads();
        partial[t] += v;
        __syncthreads();
    }
    int pref = (t>0) ? partial[t-1] : 0;
    #pragma unroll
    for(int i=0;i<8;i++){
        int o = pref + local[i];
        off[base+i] = o; cur[base+i] = o;
    }
    if (t==1023) off[NN] = partial[1023];
}

__global__ __launch_bounds__(256) void k_scatter(const int* __restrict__ dst,
    int* __restrict__ cur, int* __restrict__ eids)
{
    int e = blockIdx.x*256 + threadIdx.x;
    int p = atomicAdd(&cur[dst[e]], 1);
    eids[p] = e;
}

// ---------------- per-node input linears -> A planes ----------------
// A row layout (256): [a_so(32) | a_se(32) | a_vo_x | a_vo_y | a_vo_z | a_ve_x | a_ve_y | a_ve_z]
__global__ __launch_bounds__(256) void k_lin1(const float* __restrict__ st,
    const float* __restrict__ w_so, const float* __restrict__ w_se,
    const float* __restrict__ w_vo, const float* __restrict__ w_ve,
    float* __restrict__ A)
{
    __shared__ float wl[4][1024];
    __shared__ float sl[8][256];
    int t = threadIdx.x;
    for(int i=t;i<1024;i+=256){ wl[0][i]=w_so[i]; wl[1][i]=w_se[i]; wl[2][i]=w_vo[i]; wl[3][i]=w_ve[i]; }
    int n0 = blockIdx.x*8;
    for(int i=t;i<2048;i+=256){ int k=i>>8, c=i&255; sl[k][c]=st[(n0+k)*256+c]; }
    __syncthreads();
    for(int k=0;k<8;k++){
        float acc = 0.0f;
        if (t < 64){
            int m = t>>5, v = t&31;
            const float* w = wl[m];
            const float* s = &sl[k][m*32];
            #pragma unroll
            for(int u=0;u<32;u++) acc += s[u]*w[u*32+v];
        } else if (t < 160){
            int idx=t-64, i=idx>>5, v=idx&31;
            #pragma unroll
            for(int u=0;u<32;u++) acc += sl[k][64+u*3+i]*wl[2][u*32+v];
        } else {
            int idx=t-160, i=idx>>5, v=idx&31;
            #pragma unroll
            for(int u=0;u<32;u++) acc += sl[k][160+u*3+i]*wl[3][u*32+v];
        }
        A[(n0+k)*256 + t] = acc * INV_S32;
    }
}

// ---------------- rw2 fp32 -> bf16 B-fragment layout ----------------
// Bfrag[((ks*(NCOL/16) + nt)*64 + l)*8 + j] = rw2[k][n], k=ks*32+(l>>4)*8+j (0 if k>=100),
// n = nt*16 + (l&15).  One fragment (64 lanes x 8) is one mfma B operand.
template<int NCOL>
__global__ __launch_bounds__(256) void k_prep(const float* __restrict__ rw2, ushort* __restrict__ Bfrag)
{
    int idx = blockIdx.x*256 + threadIdx.x;      // over 128*NCOL elements
    int j = idx & 7;
    int l = (idx>>3) & 63;
    int rest = idx >> 9;                          // ks*(NCOL/16) + nt
    int nt = rest % (NCOL/16);
    int ks = rest / (NCOL/16);
    int k = ks*32 + ((l>>4)&3)*8 + j;
    int n = nt*16 + (l&15);
    float v = (k < 100) ? rw2[k*NCOL + n] : 0.0f;
    Bfrag[idx] = f2bf(v);
}

// ---------------- radial MLP via MFMA ----------------
// 64 edges/block, 256 threads (4 waves).  Phase 1: h = silu(emb@rw1/sqrt(10)) computed fp32,
// written bf16 directly in A-fragment lane order to LDS (K padded 100->128).
// Phase 2: C[64 x NCOL] = H @ RW2 with mfma_f32_16x16x32_bf16; each wave owns NTW = NCOL/64
// N-tiles x 4 M-tiles.  W written bf16 (as ushort).
template<int NCOL>
__global__ __launch_bounds__(256, 3) void k_radial_mfma(const float* __restrict__ emb,
    const float* __restrict__ rw1, const ushort* __restrict__ Bfrag,
    ushort* __restrict__ Wout)
{
    constexpr int NTW = NCOL/64;      // N-tiles per wave: 320->5, 64->1
    __shared__ __align__(16) ushort s_afrag[4*4*64*8];   // [mt][ks][l][j], 16 KB
    __shared__ float s_rw1[1000];
    __shared__ float s_emb[640];
    int t = threadIdx.x;
    int ebase = blockIdx.x*64;
    for(int i=t;i<1000;i+=256) s_rw1[i] = rw1[i];
    for(int i=t;i<640;i+=256)  s_emb[i] = emb[ebase*10 + i];
    __syncthreads();
    {   // phase 1: 4 threads per edge, each covers 16 k-pairs
        int q = t & 3, e = t >> 2;
        int mt = e >> 4, m = e & 15;
        float ev[10];
        #pragma unroll
        for(int i=0;i<10;i++) ev[i] = s_emb[e*10+i];
        #pragma unroll 2
        for(int i=0;i<16;i++){
            int p = q + 4*i;           // pair index 0..63 -> k = 2p, 2p+1
            int k0 = 2*p;
            float h0 = 0.0f, h1 = 0.0f;
            if (k0 < 100){
                float a0=0.f, a1=0.f;
                #pragma unroll
                for(int r=0;r<10;r++){
                    a0 += ev[r]*s_rw1[r*100+k0];
                    a1 += ev[r]*s_rw1[r*100+k0+1];
                }
                a0 *= INV_S10; a1 *= INV_S10;
                h0 = a0*sigmoid_f(a0);
                h1 = a1*sigmoid_f(a1);
            }
            int ks = k0 >> 5, kk = k0 & 31;
            int l  = m | ((kk>>3)<<4);
            int hw = ((mt*4+ks)*64 + l)*8 + (kk&7);
            *((uint*)&s_afrag[hw]) = (uint)f2bf(h0) | ((uint)f2bf(h1) << 16);
        }
    }
    __syncthreads();
    // phase 2: MFMA
    int w = t >> 6, l = t & 63;
    float4v acc[4][NTW];
    #pragma unroll
    for(int a=0;a<4;a++)
        #pragma unroll
        for(int b=0;b<NTW;b++)
            acc[a][b] = (float4v){0.f,0.f,0.f,0.f};
    #pragma unroll
    for(int ks=0;ks<4;ks++){
        short8 af[4];
        #pragma unroll
        for(int mt=0;mt<4;mt++)
            af[mt] = *((const short8*)&s_afrag[((mt*4+ks)*64 + l)*8]);
        #pragma unroll
        for(int ntl=0;ntl<NTW;ntl++){
            short8 bf = *((const short8*)(Bfrag + ((size_t)(ks*(NCOL/16) + w*NTW + ntl)*64 + l)*8));
            #pragma unroll
            for(int mt=0;mt<4;mt++)
                acc[mt][ntl] = __builtin_amdgcn_mfma_f32_16x16x32_bf16(af[mt], bf, acc[mt][ntl], 0, 0, 0);
        }
    }
    // epilogue: C/D map col=lane&15, row=(lane>>4)*4+reg
    int col = l & 15, rquad = l >> 4;
    #pragma unroll
    for(int mt=0;mt<4;mt++){
        #pragma unroll
        for(int ntl=0;ntl<NTW;ntl++){
            int n = (w*NTW + ntl)*16 + col;
            #pragma unroll
            for(int reg=0;reg<4;reg++){
                int eo = ebase + mt*16 + rquad*4 + reg;
                Wout[(size_t)eo*NCOL + n] = f2bf(acc[mt][ntl][reg]*0.1f);  // /sqrt(100)
            }
        }
    }
}

// ---------------- per-node message aggregation (CSR gather, atomic-free) ----------------
// nbuf row (704): [n0o 64 | n0e 64 | n1o_x 96 | n1o_y 96 | n1o_z 96 | n1e_x 96 | n1e_y 96 | n1e_z 96]
__global__ __launch_bounds__(64) void k_aggregate(const float* __restrict__ A,
    const ushort* __restrict__ W, const float* __restrict__ y0,
    const float* __restrict__ y1, const int* __restrict__ eids,
    const int* __restrict__ off, const int* __restrict__ esrc,
    float* __restrict__ nbuf)
{
    int n = blockIdx.x;
    int l = threadIdx.x;
    int u = l & 31, half = l >> 5;
    int e0 = off[n], e1 = off[n+1];
    float a_n0o0=0.f, a_n0o1=0.f, a_n0e0=0.f, a_n0e1=0.f;
    float a1o[3][3] = {{0}}, a1e[3][3] = {{0}};
    for(int p=e0;p<e1;p++){
        int e = eids[p];
        int s = esrc[e];
        float cy0 = y0[e];
        float v1x=y1[e*3+0], v1y=y1[e*3+1], v1z=y1[e*3+2];
        const float* Ar = A + s*256;
        float aso=Ar[u],      ase=Ar[32+u];
        float vox=Ar[64+u],   voy=Ar[96+u],  voz=Ar[128+u];
        float vex=Ar[160+u],  vey=Ar[192+u], vez=Ar[224+u];
        const ushort* Wr = W + (size_t)e*320;
        float w[10];
        #pragma unroll
        for(int sI=0;sI<10;sI++) w[sI] = bf2f(Wr[sI*32+u]);
        float dve = (vex*v1x+vey*v1y+vez*v1z)*INV_SQ3;
        float dvo = (vox*v1x+voy*v1y+voz*v1z)*INV_SQ3;
        float cvex=(vey*v1z-vez*v1y)*INV_SQ2, cvey=(vez*v1x-vex*v1z)*INV_SQ2, cvez=(vex*v1y-vey*v1x)*INV_SQ2;
        float cvox=(voy*v1z-voz*v1y)*INV_SQ2, cvoy=(voz*v1x-vox*v1z)*INV_SQ2, cvoz=(vox*v1y-voy*v1x)*INV_SQ2;
        a_n0o0 += w[0]*aso*cy0;
        a_n0o1 += w[1]*dve;
        a_n0e0 += w[2]*ase*cy0;
        a_n0e1 += w[3]*dvo;
        a1o[0][0]+=w[4]*ase*v1x; a1o[0][1]+=w[4]*ase*v1y; a1o[0][2]+=w[4]*ase*v1z;
        a1o[1][0]+=w[5]*vox*cy0; a1o[1][1]+=w[5]*voy*cy0; a1o[1][2]+=w[5]*voz*cy0;
        a1o[2][0]+=w[6]*cvex;    a1o[2][1]+=w[6]*cvey;    a1o[2][2]+=w[6]*cvez;
        a1e[0][0]+=w[7]*aso*v1x; a1e[0][1]+=w[7]*aso*v1y; a1e[0][2]+=w[7]*aso*v1z;
        a1e[1][0]+=w[8]*cvox;    a1e[1][1]+=w[8]*cvoy;    a1e[1][2]+=w[8]*cvoz;
        a1e[2][0]+=w[9]*vex*cy0; a1e[2][1]+=w[9]*vey*cy0; a1e[2][2]+=w[9]*vez*cy0;
    }
    float s0 = INV_SQ2*0.25f;   // m0 concat scale * seg 1/sqrt(16)
    float s1 = INV_SQ3*0.25f;   // m1 concat scale * seg
    float* nb = nbuf + n*704;
    if (half==0){
        nb[u]      = a_n0o0*s0;
        nb[32+u]   = a_n0o1*s0;
        nb[64+u]   = a_n0e0*s0;
        nb[96+u]   = a_n0e1*s0;
        #pragma unroll
        for(int sp=0;sp<3;sp++)
            #pragma unroll
            for(int i=0;i<3;i++)
                nb[128 + i*96 + sp*32 + u] = a1o[sp][i]*s1;
    } else {
        #pragma unroll
        for(int sp=0;sp<3;sp++)
            #pragma unroll
            for(int i=0;i<3;i++)
                nb[416 + i*96 + sp*32 + u] = a1e[sp][i]*s1;
    }
}

// ---------------- node update: skip + aggregated linears + nonlinearity/gating ----------------
__global__ __launch_bounds__(256) void k_update(const float* __restrict__ st,
    const float* __restrict__ nbuf,
    const float* __restrict__ wsso, const float* __restrict__ wsse,
    const float* __restrict__ wsvo, const float* __restrict__ wsve,
    const float* __restrict__ w2so, const float* __restrict__ w2se,
    const float* __restrict__ w2vo, const float* __restrict__ w2ve,
    float* __restrict__ stnew)
{
    int n = blockIdx.x, t = threadIdx.x;
    __shared__ float g[64];
    const float* sr = st + n*256;
    const float* nb = nbuf + n*704;
    if (t < 96){
        float acc1=0.f, acc2=0.f;
        #pragma unroll
        for(int u=0;u<32;u++) acc1 += sr[32+u]*wsse[u*96+t];
        for(int q=0;q<64;q++) acc2 += nb[64+q]*w2se[q*96+t];
        float o = C_S_F*INV_S32*acc1 + C_X_F*0.125f*acc2;
        if (t < 32) stnew[n*256 + 32 + t] = o*sigmoid_f(o);   // silu
        else        g[t-32] = sigmoid_f(o);
    }
    __syncthreads();
    if (t < 32){
        float acc1=0.f, acc2=0.f;
        #pragma unroll
        for(int u=0;u<32;u++) acc1 += sr[u]*wsso[u*32+t];
        for(int q=0;q<64;q++) acc2 += nb[q]*w2so[q*32+t];
        stnew[n*256+t] = tanhf(C_S_F*INV_S32*acc1 + C_X_F*0.125f*acc2);
    } else if (t >= 64 && t < 160){
        int idx=t-64, i=idx>>5, v=idx&31;
        float acc1=0.f, acc2=0.f;
        #pragma unroll
        for(int u=0;u<32;u++) acc1 += sr[64+u*3+i]*wsvo[u*32+v];
        for(int q=0;q<96;q++) acc2 += nb[128+i*96+q]*w2vo[q*32+v];
        stnew[n*256+64+v*3+i] = (C_S_F*INV_S32*acc1 + C_X_F*INV_S96*acc2)*g[v];
    } else if (t >= 160){
        int idx=t-160, i=idx>>5, v=idx&31;
        float acc1=0.f, acc2=0.f;
        #pragma unroll
        for(int u=0;u<32;u++) acc1 += sr[160+u*3+i]*wsve[u*32+v];
        for(int q=0;q<96;q++) acc2 += nb[416+i*96+q]*w2ve[q*32+v];
        stnew[n*256+160+v*3+i] = (C_S_F*INV_S32*acc1 + C_X_F*INV_S96*acc2)*g[32+v];
    }
}

// ---------------- final: node linears -> afin planes [a_se | a_vo_x | a_vo_y | a_vo_z] ----------------
__global__ __launch_bounds__(128) void k_flin(const float* __restrict__ st,
    const float* __restrict__ wse, const float* __restrict__ wvo, float* __restrict__ afin)
{
    int n = blockIdx.x, t = threadIdx.x;
    const float* sr = st + n*256;
    float acc = 0.0f;
    if (t < 32){
        #pragma unroll
        for(int u=0;u<32;u++) acc += sr[32+u]*wse[u*32+t];
    } else {
        int idx=t-32, i=idx>>5, v=idx&31;
        #pragma unroll
        for(int u=0;u<32;u++) acc += sr[64+u*3+i]*wvo[u*32+v];
    }
    afin[n*128 + t] = acc * INV_S32;
}

// ---------------- final aggregate + readout + per-graph reduction ----------------
__global__ __launch_bounds__(64) void k_fagg(const float* __restrict__ afin,
    const ushort* __restrict__ Wf, const float* __restrict__ st,
    const float* __restrict__ y0, const float* __restrict__ y1,
    const int* __restrict__ eids, const int* __restrict__ off, const int* __restrict__ esrc,
    const float* __restrict__ fsc_se, const float* __restrict__ flin2,
    const int* __restrict__ batch, float* __restrict__ out)
{
    int n = blockIdx.x, l = threadIdx.x, u = l & 31;
    int e0 = off[n], e1 = off[n+1];
    float ca=0.f, cb=0.f;
    for(int p=e0;p<e1;p++){
        int e = eids[p];
        int s = esrc[e];
        float cy0 = y0[e];
        float v1x=y1[e*3+0], v1y=y1[e*3+1], v1z=y1[e*3+2];
        const float* Ar = afin + s*128;
        float ase = Ar[u];
        float vx=Ar[32+u], vy=Ar[64+u], vz=Ar[96+u];
        float w0 = bf2f(Wf[(size_t)e*64 + u]);
        float w1 = bf2f(Wf[(size_t)e*64 + 32 + u]);
        ca += w0*ase*cy0;
        cb += w1*(vx*v1x+vy*v1y+vz*v1z)*INV_SQ3;
    }
    float f = INV_SQ2*0.25f;   // m0e concat scale * seg
    // each u computed by 2 lanes (both halves) -> 0.5 dedup factor before wave sum
    float val = 0.5f*C_X_F*0.125f*(ca*f*flin2[u] + cb*f*flin2[32+u])
              + 0.5f*C_S_F*INV_S32*(st[n*256+32+u]*fsc_se[u]);
    #pragma unroll
    for(int o=32;o>0;o>>=1) val += __shfl_xor(val, o);
    if (l==0) atomicAdd(&out[batch[n]], val*OUT_S);
}

// ---------------- host ----------------
extern "C" void kernel_launch(void* const* d_in, const int* in_sizes, int n_in,
                              void* d_out, int out_size, void* d_ws, size_t ws_size,
                              hipStream_t stream)
{
    const float* x        = (const float*)d_in[0];
    const float* edge_vec = (const float*)d_in[1];
    const float* lin1_so  = (const float*)d_in[2];
    const float* lin1_se  = (const float*)d_in[3];
    const float* lin1_vo  = (const float*)d_in[4];
    const float* lin1_ve  = (const float*)d_in[5];
    const float* sc_so    = (const float*)d_in[6];
    const float* sc_se    = (const float*)d_in[7];
    const float* sc_vo    = (const float*)d_in[8];
    const float* sc_ve    = (const float*)d_in[9];
    const float* rad_w1   = (const float*)d_in[10];
    const float* rad_w2   = (const float*)d_in[11];
    const float* lin2_so  = (const float*)d_in[12];
    const float* lin2_se  = (const float*)d_in[13];
    const float* lin2_vo  = (const float*)d_in[14];
    const float* lin2_ve  = (const float*)d_in[15];
    const float* flin1_se = (const float*)d_in[16];
    const float* flin1_vo = (const float*)d_in[17];
    const float* fsc_se   = (const float*)d_in[18];
    const float* frad_w1  = (const float*)d_in[19];
    const float* frad_w2  = (const float*)d_in[20];
    const float* flin2    = (const float*)d_in[21];
    const int*   esrc     = (const int*)d_in[22];
    const int*   edst     = (const int*)d_in[23];
    const int*   batch    = (const int*)d_in[24];
    float* out = (float*)d_out;

    uint8_t* ws = (uint8_t*)d_ws;
    size_t off = 0;
    auto alloc = [&](size_t bytes)->void* {
        void* p = ws + off;
        off += (bytes + 255) & ~(size_t)255;
        return p;
    };
    float* y0    = (float*)alloc((size_t)EE*4);
    float* y1    = (float*)alloc((size_t)EE*12);
    float* emb   = (float*)alloc((size_t)EE*40);
    int*   cnt   = (int*)  alloc((size_t)NN*4);
    int*   csro  = (int*)  alloc((size_t)(NN+1)*4);
    int*   cur   = (int*)  alloc((size_t)NN*4);
    int*   eids  = (int*)  alloc((size_t)EE*4);
    float* A     = (float*)alloc((size_t)NN*256*4);
    ushort* W    = (ushort*)alloc((size_t)EE*320*2);
    ushort* Bfrag= (ushort*)alloc((size_t)128*320*2);
    float* nbuf  = (float*)alloc((size_t)NN*704*4);
    float* st0   = (float*)alloc((size_t)NN*256*4);
    float* st1   = (float*)alloc((size_t)NN*256*4);
    float* afin  = (float*)alloc((size_t)NN*128*4);

    hipMemsetAsync(out, 0, (size_t)out_size*sizeof(float), stream);
    hipMemsetAsync(cnt, 0, (size_t)NN*4, stream);

    k_geom   <<<EE/256, 256, 0, stream>>>(edge_vec, y0, y1, emb);
    k_count  <<<EE/256, 256, 0, stream>>>(edst, cnt);
    k_scan   <<<1, 1024, 0, stream>>>(cnt, csro, cur);
    k_scatter<<<EE/256, 256, 0, stream>>>(edst, cur, eids);

    const float* st_in = x;
    float* bufs[2] = { st0, st1 };
    for (int l=0; l<3; l++){
        k_lin1<<<NN/8, 256, 0, stream>>>(st_in,
            lin1_so + l*1024, lin1_se + l*1024, lin1_vo + l*1024, lin1_ve + l*1024, A);
        k_prep<320><<<160, 256, 0, stream>>>(rad_w2 + l*32000, Bfrag);
        k_radial_mfma<320><<<EE/64, 256, 0, stream>>>(emb, rad_w1 + l*1000, Bfrag, W);
        k_aggregate<<<NN, 64, 0, stream>>>(A, W, y0, y1, eids, csro, esrc, nbuf);
        float* st_out = bufs[l & 1];
        k_update<<<NN, 256, 0, stream>>>(st_in, nbuf,
            sc_so + l*1024, sc_se + l*3072, sc_vo + l*1024, sc_ve + l*1024,
            lin2_so + l*2048, lin2_se + l*6144, lin2_vo + l*3072, lin2_ve + l*3072,
            st_out);
        st_in = st_out;
    }
    k_flin<<<NN, 128, 0, stream>>>(st_in, flin1_se, flin1_vo, afin);
    k_prep<64><<<32, 256, 0, stream>>>(frad_w2, Bfrag);
    k_radial_mfma<64><<<EE/64, 256, 0, stream>>>(emb, frad_w1, Bfrag, W);
    k_fagg<<<NN, 64, 0, stream>>>(afin, W, st_in, y0, y1, eids, csro, esrc,
                                  fsc_se, flin2, batch, out);
}